// Round 2
// 136.728 us; speedup vs baseline: 1.0150x; 1.0150x over previous
//
#include <hip/hip_runtime.h>

// MarketEncoder collapses analytically:
//   feats standardized over time  =>  mean_t(feats) == 0 exactly  =>  h = bp
//   => out[b,:] = b2 + W2 @ gelu_exact(W1 @ bp + b1), identical for all 64 rows.
// Time-series inputs and Wp never affect the output. (Verified: baseline
// version of this collapse passed with absmax 1.2e-4; weights fp32, out fp32.)
//
// R1 FAILED (absmax 1.2e-2): layer-1 used 16 lanes x one float4 = 64 of 256
// row elements — partial dot product. R2 fix: 4 sequential 64-float k-chunks
// per row group; every wave-load is 4 rows x 256 B contiguous = coalesced.
//
// Input order (setup_inputs dict): 0=close 1=high 2=low 3=open_price 4=volume
//                                  5=Wp 6=bp 7=W1 8=b1 9=W2 10=b2

#define ME_DIM 256
#define ME_HID 512
#define ME_B   64
#define NT     512

__global__ __launch_bounds__(NT) void market_encoder_const_kernel(
    const float* __restrict__ bp,   // [256]
    const float* __restrict__ W1,   // [512, 256] row-major
    const float* __restrict__ b1,   // [512]
    const float* __restrict__ W2,   // [256, 512] row-major
    const float* __restrict__ b2,   // [256]
    float* __restrict__ out)        // [64, 256] fp32
{
    __shared__ float s_bp[ME_DIM];
    __shared__ float s_g[ME_HID];
    __shared__ float s_out[ME_DIM];

    const int tid  = threadIdx.x;
    const int lane = tid & 63;
    const int wave = tid >> 6;                 // 0..7

    if (tid < ME_DIM) s_bp[tid] = bp[tid];
    __syncthreads();

    // ---- Layer 1 pre-activations: 512 rows of W1 (256 wide).
    // 16 lanes per row, 4 rows in flight per wave-iter, 64 rows/wave.
    // Full row covered via 4 k-chunks of 64 floats: lane sl reads float4 at
    // chunk*64 + sl*4. Per chunk the wave reads 4 rows x 256 B contiguous.
    {
        const int sl  = lane & 15;             // position within row group
        const int sub = lane >> 4;             // which of 4 concurrent rows
        const float4 bp0 = *(const float4*)(s_bp +   0 + sl * 4);
        const float4 bp1 = *(const float4*)(s_bp +  64 + sl * 4);
        const float4 bp2 = *(const float4*)(s_bp + 128 + sl * 4);
        const float4 bp3 = *(const float4*)(s_bp + 192 + sl * 4);
        #pragma unroll 4
        for (int it = 0; it < 16; ++it) {
            const int j = wave * 64 + it * 4 + sub;
            const float* __restrict__ wrow = W1 + j * ME_DIM;
            const float4 w0 = *(const float4*)(wrow +   0 + sl * 4);
            const float4 w1 = *(const float4*)(wrow +  64 + sl * 4);
            const float4 w2 = *(const float4*)(wrow + 128 + sl * 4);
            const float4 w3 = *(const float4*)(wrow + 192 + sl * 4);
            float p = w0.x * bp0.x + w0.y * bp0.y + w0.z * bp0.z + w0.w * bp0.w
                    + w1.x * bp1.x + w1.y * bp1.y + w1.z * bp1.z + w1.w * bp1.w
                    + w2.x * bp2.x + w2.y * bp2.y + w2.z * bp2.z + w2.w * bp2.w
                    + w3.x * bp3.x + w3.y * bp3.y + w3.z * bp3.z + w3.w * bp3.w;
            // reduce across the 16-lane group (xor 8,4,2,1 stays in-group)
            p += __shfl_xor(p, 8);
            p += __shfl_xor(p, 4);
            p += __shfl_xor(p, 2);
            p += __shfl_xor(p, 1);
            if (sl == 0) s_g[j] = p;           // lanes 0,16,32,48 -> j..j+3: no conflict
        }
    }
    __syncthreads();

    // ---- GELU: one erff per hidden unit (b1 folded in, coalesced read).
    // approximate=False => 0.5*x*(1+erf(x/sqrt2)).
    {
        const float x = s_g[tid] + b1[tid];
        s_g[tid] = 0.5f * x * (1.0f + erff(x * 0.70710678118654752440f));
    }
    __syncthreads();

    // ---- Layer 2: 256 rows of W2 (512 wide). Whole wave per row:
    // lane holds g[lane*4] and g[256+lane*4] (hoisted); W2 row read as two
    // dense coalesced 1 KB float4 wave-loads. 32 rows per wave.
    {
        const float4 ga = *(const float4*)(s_g + lane * 4);
        const float4 gb = *(const float4*)(s_g + ME_DIM + lane * 4);
        #pragma unroll 4
        for (int r = 0; r < 32; ++r) {
            const int d = wave * 32 + r;
            const float* __restrict__ wrow = W2 + d * ME_HID;
            const float4 wa = *(const float4*)(wrow + lane * 4);
            const float4 wb = *(const float4*)(wrow + ME_DIM + lane * 4);
            float p = wa.x * ga.x + wa.y * ga.y + wa.z * ga.z + wa.w * ga.w
                    + wb.x * gb.x + wb.y * gb.y + wb.z * gb.z + wb.w * gb.w;
            p += __shfl_xor(p, 32);
            p += __shfl_xor(p, 16);
            p += __shfl_xor(p, 8);
            p += __shfl_xor(p, 4);
            p += __shfl_xor(p, 2);
            p += __shfl_xor(p, 1);
            if (lane == 0) s_out[d] = b2[d] + p;
        }
    }
    __syncthreads();

    // Block b writes batch row b (256 consecutive fp32, coalesced).
    if (tid < ME_DIM) out[blockIdx.x * ME_DIM + tid] = s_out[tid];
}

extern "C" void kernel_launch(void* const* d_in, const int* in_sizes, int n_in,
                              void* d_out, int out_size, void* d_ws, size_t ws_size,
                              hipStream_t stream) {
    (void)in_sizes; (void)n_in; (void)out_size; (void)d_ws; (void)ws_size;

    const float* bp = (const float*)d_in[6];
    const float* W1 = (const float*)d_in[7];
    const float* b1 = (const float*)d_in[8];
    const float* W2 = (const float*)d_in[9];
    const float* b2 = (const float*)d_in[10];
    float* out = (float*)d_out;

    market_encoder_const_kernel<<<ME_B, NT, 0, stream>>>(bp, W1, b1, W2, b2, out);
}